// Round 7
// baseline (724.598 us; speedup 1.0000x reference)
//
#include <hip/hip_runtime.h>
#include <hip/hip_bf16.h>

// Problem constants (from reference): B,Q,C,P,A = 32,300,81,300,29
#define BB 32
#define QQ 300
#define CC 81
#define PP 300
#define AA 29

// Flat output layout (fp32 elements), concatenated in reference return order:
// scores(B,Q) | labels(B,Q) | boxes(B,Q,4) | score(B,A,Q,Q+1) | h_mask(B,Q) | o_mask(B,Q+1)
constexpr long long OFF_SCORES = 0;
constexpr long long OFF_LABELS = OFF_SCORES + (long long)BB * QQ;            // 9600
constexpr long long OFF_BOXES  = OFF_LABELS + (long long)BB * QQ;            // 19200
constexpr long long OFF_SCORE  = OFF_BOXES  + (long long)BB * QQ * 4;        // 57600
constexpr long long SCORE_ELEMS = (long long)BB * AA * QQ * (QQ + 1);        // 83,798,400
constexpr long long OFF_HMASK  = OFF_SCORE + SCORE_ELEMS;                    // 83,856,000
constexpr long long OFF_OMASK  = OFF_HMASK + (long long)BB * QQ;             // 83,865,600
// total = 83,875,232 elements

constexpr int SLOTS = QQ * (QQ + 1);          // 90,300 slots per (b,a) plane
constexpr int N4 = (int)(SCORE_ELEMS / 4);    // 20,949,600 float4 (exact)
constexpr int NBLK = 2048;                    // total blocks
constexpr int SCT_BLOCKS = BB;                // blocks 0..31: cls + scatter epilogue
constexpr int FILL_BLOCKS = NBLK - SCT_BLOCKS;// blocks 32..2047: zero-fill

typedef float f32x4 __attribute__((ext_vector_type(4)));

// ---------------------------------------------------------------------------
// Session ledger (dur_us total; ~330us fixed harness tax incl. ~230us poison fill):
//   R0 memset+scatter(320t)          396.7   best so far
//   R1 NT-store fill + scatter       424.6   NT 16B stores lose vs cached fill
//   R2 LUT + fused writer (a-fast)   414.1   29x LUT re-read
//   R3 LUT + fused writer (reg-LUT)  431.6   plane-strided stores
//   R6 memset+scatter(512t)          412.2   == R0 structure; noise ~ +-15us
// R7: single fused dispatch — plain-store fill (2016 blocks) + cls/scatter in
// 32 spin-wait epilogue blocks (threadfence + device-scope counter). Collapses
// 4 dispatches -> 2 (4B ctr memset + fused). Pre-committed: if >= ~395, the
// floor (fixed tax + mandatory 335MB write at fill BW) is reached -> ROOFLINE.
// ---------------------------------------------------------------------------

__global__ __launch_bounds__(256) void fused_kernel(const float* __restrict__ logits,
                                                    const float* __restrict__ boxes_in,
                                                    const float* __restrict__ tsize,
                                                    const int* __restrict__ pairs,
                                                    const float* __restrict__ actions,
                                                    float* __restrict__ out,
                                                    int* __restrict__ ctr) {
    const int bid = blockIdx.x;
    const int tid = threadIdx.x;

    if (bid >= SCT_BLOCKS) {
        // ---- fill role: zero the score region with plain cached f32x4 stores
        f32x4* p = (f32x4*)(out + OFF_SCORE);
        f32x4 z = (f32x4)0.0f;
        for (int i = (bid - SCT_BLOCKS) * 256 + tid; i < N4; i += FILL_BLOCKS * 256) {
            p[i] = z;
        }
        __threadfence();          // make this thread's zeros device-visible
        __syncthreads();          // all threads of block fenced
        if (tid == 0) {
            __hip_atomic_fetch_add(ctr, 1, __ATOMIC_RELEASE, __HIP_MEMORY_SCOPE_AGENT);
        }
        return;
    }

    // ---- cls + scatter role: this block owns batch b = bid
    const int b = bid;

    // cls/box/mask for q in [0,300) of this batch (verified math since R0)
    for (int q = tid; q < QQ; q += 256) {
        int t = b * QQ + q;
        const float* l = logits + (long long)t * CC;
        float m = -1e30f, best = -1e30f;
        int am = 0;
        for (int c = 0; c < CC; ++c) {
            float x = l[c];
            m = fmaxf(m, x);
            if (c < CC - 1 && x > best) { best = x; am = c; }
        }
        float s = 0.0f;
        for (int c = 0; c < CC; ++c) s += __expf(l[c] - m);
        float score = __expf(best - m) / s;

        out[OFF_SCORES + t] = score;
        out[OFF_LABELS + t] = (float)am;

        float cx = boxes_in[4 * (long long)t + 0];
        float cy = boxes_in[4 * (long long)t + 1];
        float w  = boxes_in[4 * (long long)t + 2];
        float h  = boxes_in[4 * (long long)t + 3];
        float img_h = tsize[2 * b + 0];
        float img_w = tsize[2 * b + 1];
        out[OFF_BOXES + 4 * (long long)t + 0] = (cx - 0.5f * w) * img_w;
        out[OFF_BOXES + 4 * (long long)t + 1] = (cy - 0.5f * h) * img_h;
        out[OFF_BOXES + 4 * (long long)t + 2] = (cx + 0.5f * w) * img_w;
        out[OFF_BOXES + 4 * (long long)t + 3] = (cy + 0.5f * h) * img_h;

        out[OFF_HMASK + t] = (am == 1 && score > 0.0f) ? 1.0f : 0.0f;
        out[OFF_OMASK + (long long)b * (QQ + 1) + q] = (score > 0.0f) ? 1.0f : 0.0f;
        if (q == 0) out[OFF_OMASK + (long long)b * (QQ + 1) + QQ] = 1.0f;
    }

    // keys + numpy-last-wins winners (overlapped with the fill)
    __shared__ int s_key[PP];
    __shared__ int s_win[PP];
    __shared__ int nz;
    if (tid == 0) nz = 0;
    __syncthreads();
    // int64-vs-int32 auto-detect must be a GLOBAL decision: scan all odd words
    int local = 0;
    for (int i = tid; i < BB * PP; i += 256) local |= pairs[2 * i + 1];
    if (local) atomicOr(&nz, 1);
    __syncthreads();
    bool is64 = (nz == 0);

    for (int pp = tid; pp < PP; pp += 256) {
        int h, o;
        if (is64) {
            h = pairs[((long long)(b * PP + pp)) * 4 + 0];
            o = pairs[((long long)(b * PP + pp)) * 4 + 2];
        } else {
            h = pairs[((long long)(b * PP + pp)) * 2 + 0];
            o = pairs[((long long)(b * PP + pp)) * 2 + 1];
        }
        if (h == o) o = QQ;
        s_key[pp] = h * (QQ + 1) + o;
    }
    __syncthreads();
    for (int pp = tid; pp < PP; pp += 256) {
        int k = s_key[pp];
        int win = 1;
        for (int p2 = pp + 1; p2 < PP; ++p2) {
            if (s_key[p2] == k) { win = 0; break; }  // later pair wins
        }
        s_win[pp] = win;
    }
    __syncthreads();

    // wait until every fill block has published its zeros
    if (tid == 0) {
        while (__hip_atomic_load(ctr, __ATOMIC_ACQUIRE, __HIP_MEMORY_SCOPE_AGENT) < FILL_BLOCKS) {
            __builtin_amdgcn_s_sleep(8);
        }
    }
    __syncthreads();

    // scatter sigmoid(actions) for winning pairs of this batch
    const float* actb = actions + (long long)b * PP * AA;
    float* scoreb = out + OFF_SCORE + (long long)b * AA * SLOTS;
    for (int i = tid; i < PP * AA; i += 256) {
        int p = i / AA;
        int a = i - p * AA;       // consecutive lanes: contiguous actions loads
        if (!s_win[p]) continue;
        float x = actb[i];
        float sg = 1.0f / (1.0f + __expf(-x));
        scoreb[(long long)a * SLOTS + s_key[p]] = sg;
    }
}

// ---------------------------------------------------------------------------
// Fallback path (no workspace): R0/R6 verified structure.
__global__ void cls_box_mask_kernel(const float* __restrict__ logits,
                                    const float* __restrict__ boxes_in,
                                    const float* __restrict__ tsize,
                                    float* __restrict__ out) {
    int t = blockIdx.x * blockDim.x + threadIdx.x;
    if (t >= BB * QQ) return;
    int b = t / QQ;
    int q = t - b * QQ;
    const float* l = logits + (long long)t * CC;
    float m = -1e30f, best = -1e30f;
    int am = 0;
    for (int c = 0; c < CC; ++c) {
        float x = l[c];
        m = fmaxf(m, x);
        if (c < CC - 1 && x > best) { best = x; am = c; }
    }
    float s = 0.0f;
    for (int c = 0; c < CC; ++c) s += __expf(l[c] - m);
    float score = __expf(best - m) / s;
    out[OFF_SCORES + t] = score;
    out[OFF_LABELS + t] = (float)am;
    float cx = boxes_in[4 * (long long)t + 0];
    float cy = boxes_in[4 * (long long)t + 1];
    float w  = boxes_in[4 * (long long)t + 2];
    float h  = boxes_in[4 * (long long)t + 3];
    float img_h = tsize[2 * b + 0];
    float img_w = tsize[2 * b + 1];
    out[OFF_BOXES + 4 * (long long)t + 0] = (cx - 0.5f * w) * img_w;
    out[OFF_BOXES + 4 * (long long)t + 1] = (cy - 0.5f * h) * img_h;
    out[OFF_BOXES + 4 * (long long)t + 2] = (cx + 0.5f * w) * img_w;
    out[OFF_BOXES + 4 * (long long)t + 3] = (cy + 0.5f * h) * img_h;
    out[OFF_HMASK + t] = (am == 1 && score > 0.0f) ? 1.0f : 0.0f;
    out[OFF_OMASK + (long long)b * (QQ + 1) + q] = (score > 0.0f) ? 1.0f : 0.0f;
    if (q == 0) out[OFF_OMASK + (long long)b * (QQ + 1) + QQ] = 1.0f;
}

__global__ void scatter_kernel(const int* __restrict__ pairs,
                               const float* __restrict__ actions,
                               float* __restrict__ out) {
    __shared__ int s_key[PP];
    __shared__ int s_win[PP];
    __shared__ int nz;
    int tid = threadIdx.x;
    int b = blockIdx.x;
    if (tid == 0) nz = 0;
    __syncthreads();
    int local = 0;
    for (int i = tid; i < BB * PP; i += blockDim.x) local |= pairs[2 * i + 1];
    if (local) atomicOr(&nz, 1);
    __syncthreads();
    bool is64 = (nz == 0);
    if (tid < PP) {
        int h, o;
        if (is64) {
            h = pairs[((long long)(b * PP + tid)) * 4 + 0];
            o = pairs[((long long)(b * PP + tid)) * 4 + 2];
        } else {
            h = pairs[((long long)(b * PP + tid)) * 2 + 0];
            o = pairs[((long long)(b * PP + tid)) * 2 + 1];
        }
        if (h == o) o = QQ;
        s_key[tid] = h * (QQ + 1) + o;
    }
    __syncthreads();
    if (tid < PP) {
        int k = s_key[tid];
        int win = 1;
        for (int p2 = tid + 1; p2 < PP; ++p2) {
            if (s_key[p2] == k) { win = 0; break; }
        }
        s_win[tid] = win;
    }
    __syncthreads();
    const float* actb = actions + (long long)b * PP * AA;
    float* scoreb = out + OFF_SCORE + (long long)b * AA * SLOTS;
    for (int i = tid; i < PP * AA; i += 512) {
        int p = i / AA;
        int a = i - p * AA;
        if (!s_win[p]) continue;
        float x = actb[i];
        float sg = 1.0f / (1.0f + __expf(-x));
        scoreb[(long long)a * SLOTS + s_key[p]] = sg;
    }
}

extern "C" void kernel_launch(void* const* d_in, const int* in_sizes, int n_in,
                              void* d_out, int out_size, void* d_ws, size_t ws_size,
                              hipStream_t stream) {
    const float* logits   = (const float*)d_in[0]; // (B,Q,C)
    const float* boxes_in = (const float*)d_in[1]; // (B,Q,4)
    const float* actions  = (const float*)d_in[2]; // (B,P,A)
    const int*   pairs    = (const int*)d_in[3];   // (B,P,2) int
    const float* tsize    = (const float*)d_in[4]; // (B,2)
    float* out = (float*)d_out;

    if (d_ws != nullptr && ws_size >= sizeof(int)) {
        int* ctr = (int*)d_ws;
        hipMemsetAsync(ctr, 0, sizeof(int), stream);   // reset arrival counter
        fused_kernel<<<NBLK, 256, 0, stream>>>(logits, boxes_in, tsize, pairs,
                                               actions, out, ctr);
    } else {
        hipMemsetAsync((char*)d_out + OFF_SCORE * sizeof(float), 0,
                       (size_t)SCORE_ELEMS * sizeof(float), stream);
        int n = BB * QQ;
        cls_box_mask_kernel<<<(n + 255) / 256, 256, 0, stream>>>(logits, boxes_in, tsize, out);
        scatter_kernel<<<BB, 512, 0, stream>>>(pairs, actions, out);
    }
}

// Round 8
// 411.932 us; speedup vs baseline: 1.7590x; 1.7590x over previous
//
#include <hip/hip_runtime.h>
#include <hip/hip_bf16.h>

// Problem constants (from reference): B,Q,C,P,A = 32,300,81,300,29
#define BB 32
#define QQ 300
#define CC 81
#define PP 300
#define AA 29

// Flat output layout (fp32 elements), concatenated in reference return order:
// scores(B,Q) | labels(B,Q) | boxes(B,Q,4) | score(B,A,Q,Q+1) | h_mask(B,Q) | o_mask(B,Q+1)
constexpr long long OFF_SCORES = 0;
constexpr long long OFF_LABELS = OFF_SCORES + (long long)BB * QQ;            // 9600
constexpr long long OFF_BOXES  = OFF_LABELS + (long long)BB * QQ;            // 19200
constexpr long long OFF_SCORE  = OFF_BOXES  + (long long)BB * QQ * 4;        // 57600
constexpr long long SCORE_ELEMS = (long long)BB * AA * QQ * (QQ + 1);        // 83,798,400
constexpr long long OFF_HMASK  = OFF_SCORE + SCORE_ELEMS;                    // 83,856,000
constexpr long long OFF_OMASK  = OFF_HMASK + (long long)BB * QQ;             // 83,865,600
// total = 83,875,232 elements

constexpr int SLOTS = QQ * (QQ + 1);          // 90,300 slots per (b,a) plane

// ---------------------------------------------------------------------------
// Session ledger (dur_us total):
//   R0 memset+scatter(320t)          396.7   best
//   R1 NT-store fill + scatter       424.6   custom NT fill ~3.9 TB/s < rocclr 5.7
//   R2 LUT + fused writer (a-fast)   414.1   29x LUT re-read
//   R3 LUT + fused writer (reg-LUT)  431.6   plane-strided stores
//   R6 memset+scatter(512t)          412.2   == R0 structure; noise ~ +-15us
//   R7 single-dispatch spin-wait     724.6   FUSION POISONED: per-block agent-scope
//      release fences (threadfence+atomic) force per-XCD L2 writebacks; fill ran
//      at 780 GB/s, VALUBusy 0.6%. Also calibrated: WRITE_SIZE is accurate; the
//      rocclr fill path genuinely sustains ~5.7 TB/s (near fill ceiling).
// R8: revert to the proven structure; merge cls+scatter into ONE per-batch
// kernel (both verified inside R7's epilogue blocks). 2 dispatches total.
// Controllable floor: 335 MB fill @ 5.7 TB/s (~59us) + ~10us compute.
// ---------------------------------------------------------------------------

// One block per batch b (512 threads): cls/box/mask for the batch's 300 queries,
// then scatter sigmoid(actions) for numpy-last-wins pairs. No inter-block deps.
__global__ void postproc_kernel(const float* __restrict__ logits,
                                const float* __restrict__ boxes_in,
                                const float* __restrict__ tsize,
                                const int* __restrict__ pairs,
                                const float* __restrict__ actions,
                                float* __restrict__ out) {
    const int b = blockIdx.x;
    const int tid = threadIdx.x;

    // ---- cls/box/mask (math verified since R0; per-batch-block form verified R7)
    for (int q = tid; q < QQ; q += blockDim.x) {
        int t = b * QQ + q;
        const float* l = logits + (long long)t * CC;
        // global max (all 81) + max/argmax over first 80 (first-index tie-break)
        float m = -1e30f, best = -1e30f;
        int am = 0;
        for (int c = 0; c < CC; ++c) {
            float x = l[c];
            m = fmaxf(m, x);
            if (c < CC - 1 && x > best) { best = x; am = c; }
        }
        float s = 0.0f;
        for (int c = 0; c < CC; ++c) s += __expf(l[c] - m);
        float score = __expf(best - m) / s;

        out[OFF_SCORES + t] = score;
        out[OFF_LABELS + t] = (float)am;

        float cx = boxes_in[4 * (long long)t + 0];
        float cy = boxes_in[4 * (long long)t + 1];
        float w  = boxes_in[4 * (long long)t + 2];
        float h  = boxes_in[4 * (long long)t + 3];
        float img_h = tsize[2 * b + 0];
        float img_w = tsize[2 * b + 1];
        out[OFF_BOXES + 4 * (long long)t + 0] = (cx - 0.5f * w) * img_w;
        out[OFF_BOXES + 4 * (long long)t + 1] = (cy - 0.5f * h) * img_h;
        out[OFF_BOXES + 4 * (long long)t + 2] = (cx + 0.5f * w) * img_w;
        out[OFF_BOXES + 4 * (long long)t + 3] = (cy + 0.5f * h) * img_h;

        // masks (threshold = 0.0)
        out[OFF_HMASK + t] = (am == 1 && score > 0.0f) ? 1.0f : 0.0f;
        out[OFF_OMASK + (long long)b * (QQ + 1) + q] = (score > 0.0f) ? 1.0f : 0.0f;
        if (q == 0) out[OFF_OMASK + (long long)b * (QQ + 1) + QQ] = 1.0f;
    }

    // ---- pair keys + numpy-last-wins winners
    __shared__ int s_key[PP];
    __shared__ int s_win[PP];
    __shared__ int nz;
    if (tid == 0) nz = 0;
    __syncthreads();
    // int64-vs-int32 auto-detect is a GLOBAL property: scan all odd 32-bit words
    // (pair values are in [0,300), so int64 little-endian => odd words all zero).
    int local = 0;
    for (int i = tid; i < BB * PP; i += blockDim.x) local |= pairs[2 * i + 1];
    if (local) atomicOr(&nz, 1);
    __syncthreads();
    bool is64 = (nz == 0);

    for (int pp = tid; pp < PP; pp += blockDim.x) {
        int h, o;
        if (is64) {
            h = pairs[((long long)(b * PP + pp)) * 4 + 0];
            o = pairs[((long long)(b * PP + pp)) * 4 + 2];
        } else {
            h = pairs[((long long)(b * PP + pp)) * 2 + 0];
            o = pairs[((long long)(b * PP + pp)) * 2 + 1];
        }
        if (h == o) o = QQ;
        s_key[pp] = h * (QQ + 1) + o;
    }
    __syncthreads();
    for (int pp = tid; pp < PP; pp += blockDim.x) {
        int k = s_key[pp];
        int win = 1;
        for (int p2 = pp + 1; p2 < PP; ++p2) {
            if (s_key[p2] == k) { win = 0; break; }  // a later pair wins the slot
        }
        s_win[pp] = win;
    }
    __syncthreads();

    // ---- scatter sigmoid(actions) for winning pairs (8700 items over the block)
    const float* actb = actions + (long long)b * PP * AA;
    float* scoreb = out + OFF_SCORE + (long long)b * AA * SLOTS;
    for (int i = tid; i < PP * AA; i += blockDim.x) {
        int p = i / AA;
        int a = i - p * AA;          // consecutive lanes: contiguous actions loads
        if (!s_win[p]) continue;
        float x = actb[i];
        float sg = 1.0f / (1.0f + __expf(-x));
        scoreb[(long long)a * SLOTS + s_key[p]] = sg;
    }
}

extern "C" void kernel_launch(void* const* d_in, const int* in_sizes, int n_in,
                              void* d_out, int out_size, void* d_ws, size_t ws_size,
                              hipStream_t stream) {
    const float* logits   = (const float*)d_in[0]; // (B,Q,C)
    const float* boxes_in = (const float*)d_in[1]; // (B,Q,4)
    const float* actions  = (const float*)d_in[2]; // (B,P,A)
    const int*   pairs    = (const int*)d_in[3];   // (B,P,2) int
    const float* tsize    = (const float*)d_in[4]; // (B,2)
    float* out = (float*)d_out;

    // Zero the score region via the rocclr fill path: ~5.7 TB/s measured
    // (calibrated via R7's accurate WRITE_SIZE; fastest observed writer of this
    // buffer — our NT/plain/fused variants all measured slower, see ledger).
    hipMemsetAsync((char*)d_out + OFF_SCORE * sizeof(float), 0,
                   (size_t)SCORE_ELEMS * sizeof(float), stream);

    // One kernel for everything else (stream order provides memset->kernel
    // ordering; no device fences needed — R7 showed those are the poison).
    postproc_kernel<<<BB, 512, 0, stream>>>(logits, boxes_in, tsize, pairs,
                                            actions, out);
}